// Round 10
// baseline (41.829 us; speedup 1.0000x reference)
//
#include <hip/hip_runtime.h>
#include <math.h>

#define N_IMG 64
#define H_IMG 512
#define W_IMG 512
#define EPSF 1e-6f
#define LN2F 0.69314718055994530942f

#define SLAB_ROWS 8
#define SLABS (H_IMG / SLAB_ROWS)      // 64 slabs per image
#define NBLK (N_IMG * SLABS)           // 4096 main blocks
#define WSSTRIDE 20
// slot: [0]=bce_log2_sum, [1]=fd_diff, [2]=fd_cnt, [3..10]=patch_d[8], [11..18]=patch_cnt[8]

typedef float floatx4 __attribute__((ext_vector_type(4)));   // clang-native vec4

__device__ __forceinline__ float wave_reduce_add(float v) {
#pragma unroll
    for (int off = 32; off > 0; off >>= 1)
        v += __shfl_down(v, off, 64);
    return v;  // valid in lane 0
}

// non-temporal 16B load: nt cache policy, no LLC allocation on fill
__device__ __forceinline__ floatx4 ldnt(const float* p) {
    return __builtin_nontemporal_load(reinterpret_cast<const floatx4*>(p));
}

__global__ __launch_bounds__(256, 8) void loss_main(
    const float* __restrict__ pred, const float* __restrict__ gt,
    float* __restrict__ ws)
{
    __shared__ float l_pd[2][8], l_pc[2][8], l_s[4][3];

    const int b    = blockIdx.x;
    const int n    = b >> 6;           // image
    const int slab = b & 63;           // 8-row slab
    const int tid  = threadIdx.x;
    const int w    = tid >> 6;         // wave 0..3
    const int lane = tid & 63;
    const int pr   = tid >> 7;         // 4-row half within slab (0..1)
    const int pcc  = tid & 127;        // 4-col cell index

    // thread owns one 4x4 fd pool cell
    const size_t base = ((size_t)(n * H_IMG + slab * SLAB_ROWS + pr * 4)) * W_IMG
                      + (size_t)(pcc * 4);
    const float* pb = pred + base;
    const float* gb = gt + base;

    // ---- 8 dwordx4 loads, non-temporal ----
    const floatx4 P0 = ldnt(pb);
    const floatx4 P1 = ldnt(pb + W_IMG);
    const floatx4 P2 = ldnt(pb + 2 * W_IMG);
    const floatx4 P3 = ldnt(pb + 3 * W_IMG);
    const floatx4 G0 = ldnt(gb);
    const floatx4 G1 = ldnt(gb + W_IMG);
    const floatx4 G2 = ldnt(gb + 2 * W_IMG);
    const floatx4 G3 = ldnt(gb + 3 * W_IMG);

    float bce = 0.f, pdsum = 0.f, gsum = 0.f, ssum = 0.f;
    {
        const float pv[16] = {P0.x,P0.y,P0.z,P0.w, P1.x,P1.y,P1.z,P1.w,
                              P2.x,P2.y,P2.z,P2.w, P3.x,P3.y,P3.z,P3.w};
        const float gv[16] = {G0.x,G0.y,G0.z,G0.w, G1.x,G1.y,G1.z,G1.w,
                              G2.x,G2.y,G2.z,G2.w, G3.x,G3.y,G3.z,G3.w};
#pragma unroll
        for (int i = 0; i < 16; ++i) {
            const float p = pv[i], g = gv[i];
            // gt exactly 0/1: g*ln(p)+(1-g)*ln(1-p) == ln(g ? p : 1-p); accumulate log2
            bce   += __log2f(g > 0.5f ? p : 1.0f - p);
            const float sig = __builtin_amdgcn_rcpf(1.0f + __expf(-p));
            pdsum += fabsf(sig - g);
            gsum  += g;              // == count(g>0), also fd cell gt-sum
            ssum  += sig;
        }
    }

    // ---- fd loss: this thread's 4x4 cell ----
    const float m0r = ssum * 0.0625f, m1r = gsum * 0.0625f;
    const float m0 = (m0r > 0.f && m0r < 16.f) ? m0r : 0.f;
    const float m1 = (m1r > 0.f && m1r < 16.f) ? m1r : 0.f;
    float fdd = fabsf(m0 - m1);
    float fdc = (m1 > 0.f) ? 1.f : 0.f;

    // ---- block reduce bce/fdd/fdc ----
    {
        const float b0 = wave_reduce_add(bce);
        const float b1 = wave_reduce_add(fdd);
        const float b2 = wave_reduce_add(fdc);
        if (lane == 0) { l_s[w][0] = b0; l_s[w][1] = b1; l_s[w][2] = b2; }
    }

    // ---- patch partials: 16 consecutive lanes share one 64-col patch column ----
    {
        float d = pdsum, ct = gsum;
        d += __shfl_down(d, 8, 64);  ct += __shfl_down(ct, 8, 64);
        d += __shfl_down(d, 4, 64);  ct += __shfl_down(ct, 4, 64);
        d += __shfl_down(d, 2, 64);  ct += __shfl_down(ct, 2, 64);
        d += __shfl_down(d, 1, 64);  ct += __shfl_down(ct, 1, 64);
        if ((lane & 15) == 0) {
            const int col = (w & 1) * 4 + (lane >> 4);   // patch col 0..7
            l_pd[pr][col] = d;
            l_pc[pr][col] = ct;
        }
    }
    __syncthreads();

    float* slot = ws + (size_t)b * WSSTRIDE;
    if (tid == 0) {
        slot[0] = l_s[0][0] + l_s[1][0] + l_s[2][0] + l_s[3][0];
        slot[1] = l_s[0][1] + l_s[1][1] + l_s[2][1] + l_s[3][1];
        slot[2] = l_s[0][2] + l_s[1][2] + l_s[2][2] + l_s[3][2];
    }
    if (tid < 8) {
        slot[3  + tid] = l_pd[0][tid] + l_pd[1][tid];
        slot[11 + tid] = l_pc[0][tid] + l_pc[1][tid];
    }
}

__global__ __launch_bounds__(256) void loss_finalize(
    const float* __restrict__ ws, float* __restrict__ out)
{
    __shared__ float l_a[12];
    __shared__ float l_part[256];
    __shared__ float l_cell[64][2];    // 8x8 patch grid: [cell][0]=dsum, [1]=cnt
    const int tid = threadIdx.x;

    // Phase A: bce / fd sums over all 4096 block slots
    float a0 = 0.f, a1 = 0.f, a2 = 0.f;
    for (int b = tid; b < NBLK; b += 256) {
        const float* p = ws + (size_t)b * WSSTRIDE;
        a0 += p[0]; a1 += p[1]; a2 += p[2];
    }
    a0 = wave_reduce_add(a0);
    a1 = wave_reduce_add(a1);
    a2 = wave_reduce_add(a2);
    if ((tid & 63) == 0) {
        const int w = tid >> 6;
        l_a[w * 3 + 0] = a0; l_a[w * 3 + 1] = a1; l_a[w * 3 + 2] = a2;
    }

    // Phase B: 64 cells x {dsum,cnt} x 2 image-halves
    {
        const int cell = tid >> 2, sel = (tid >> 1) & 1, half = tid & 1;
        const int prow = cell >> 3, pcol = cell & 7;
        const int ofs = (sel ? 11 : 3) + pcol;
        float s = 0.f;
        const int n0 = half * 32;
        for (int n = n0; n < n0 + 32; ++n) {
            const int bb = n * SLABS + prow * 8;   // 8 slabs per 64-row patch row
#pragma unroll
            for (int q = 0; q < 8; ++q)
                s += ws[(size_t)(bb + q) * WSSTRIDE + ofs];
        }
        l_part[tid] = s;
    }
    __syncthreads();
    if (tid < 128) {
        const int cell = tid >> 1, sel = tid & 1;
        l_cell[cell][sel] = l_part[cell * 4 + sel * 2] + l_part[cell * 4 + sel * 2 + 1];
    }
    __syncthreads();

    if (tid != 0) return;

    const float Nf = (float)N_IMG;
    const float bce_sum = (l_a[0] + l_a[3] + l_a[6] + l_a[9]) * LN2F;  // log2 -> ln
    const float fd_d    = l_a[1] + l_a[4] + l_a[7] + l_a[10];
    const float fd_c    = l_a[2] + l_a[5] + l_a[8] + l_a[11];

    const float bce = -bce_sum / (float)((size_t)N_IMG * H_IMG * W_IMG);

    // fd loss
    const float cfd = fd_d / fmaxf(fd_c, EPSF);
    const float vessel = sqrtf(Nf * 512.f * cfd * cfd);
    float st2 = 0.f;
    for (int j = 9; j >= 2; --j) { const float s = exp2f((float)j); st2 += s * s; }
    const float loss_fd = vessel / sqrtf(st2) / Nf;

    // patch loss
    float total = 0.f;
    {   // ps=64: 8x8 grid
        float ts = 0.f;
        for (int i = 0; i < 64; ++i) {
            const float cc = l_cell[i][0] / fmaxf(l_cell[i][1], EPSF);
            ts += 64.f * Nf * cc * cc;
        }
        float local = sqrtf(ts) / 512.f / Nf;
        total += fminf(fmaxf(local, 0.f), 1.f);
    }
    {   // ps=128: 2x2 aggregation
        float ts = 0.f;
        for (int i = 0; i < 4; ++i) for (int j = 0; j < 4; ++j) {
            float d = 0.f, c = 0.f;
            for (int a = 0; a < 2; ++a) for (int bq = 0; bq < 2; ++bq) {
                const int idx = (2 * i + a) * 8 + (2 * j + bq);
                d += l_cell[idx][0]; c += l_cell[idx][1];
            }
            const float cc = d / fmaxf(c, EPSF);
            ts += 128.f * Nf * cc * cc;
        }
        float local = sqrtf(ts) / 512.f / Nf;
        total += fminf(fmaxf(local, 0.f), 1.f);
    }
    {   // ps=256: 4x4 aggregation
        float ts = 0.f;
        for (int i = 0; i < 2; ++i) for (int j = 0; j < 2; ++j) {
            float d = 0.f, c = 0.f;
            for (int a = 0; a < 4; ++a) for (int bq = 0; bq < 4; ++bq) {
                const int idx = (4 * i + a) * 8 + (4 * j + bq);
                d += l_cell[idx][0]; c += l_cell[idx][1];
            }
            const float cc = d / fmaxf(c, EPSF);
            ts += 256.f * Nf * cc * cc;
        }
        float local = sqrtf(ts) / 512.f / Nf;
        total += fminf(fmaxf(local, 0.f), 1.f);
    }
    const float loss_patch = total / 64.f;   // (512/64)^2

    out[0] = 1.1f * bce + 0.02f * loss_fd + 0.03f * loss_patch;
}

extern "C" void kernel_launch(void* const* d_in, const int* in_sizes, int n_in,
                              void* d_out, int out_size, void* d_ws, size_t ws_size,
                              hipStream_t stream)
{
    const float* pred = (const float*)d_in[0];
    const float* gt   = (const float*)d_in[1];
    float* ws  = (float*)d_ws;
    float* out = (float*)d_out;

    // every ws slot is fully written by loss_main each call: no memset needed
    loss_main<<<NBLK, 256, 0, stream>>>(pred, gt, ws);
    loss_finalize<<<1, 256, 0, stream>>>(ws, out);
}